// Round 1
// baseline (1181.463 us; speedup 1.0000x reference)
//
#include <hip/hip_runtime.h>
#include <math.h>

namespace {
constexpr int Bc = 64, Lc = 256, DMc = 256, NHc = 4, DKc = 64;
constexpr int NTc = 20, START_c = 18, STOP_c = 19;
constexpr int ROWSc = Bc * Lc;  // 16384
}

// ---------------- fin = concat(emb1[sent], emb2[bush], pinyin, trans_weizhi, weizhi) ----------------
__global__ __launch_bounds__(256) void build_fin_k(
    const int* __restrict__ sent, const int* __restrict__ bush,
    const float* __restrict__ pin, const float* __restrict__ wz,
    const float* __restrict__ twz, const float* __restrict__ emb1,
    const float* __restrict__ emb2, float* __restrict__ fin) {
  const int row = blockIdx.x;
  const int c = threadIdx.x;
  float v;
  if (c < 100)      v = emb1[(size_t)sent[row] * 100 + c];
  else if (c < 200) v = emb2[(size_t)bush[row] * 100 + (c - 100)];
  else if (c < 220) v = pin[(size_t)row * 20 + (c - 200)];
  else if (c < 238) v = twz[(size_t)row * 18 + (c - 220)];
  else              v = wz[(size_t)row * 18 + (c - 238)];
  fin[(size_t)row * 256 + c] = v;
}

// ---------------- C[m,n] = sum_k A[m,k]*W[n,k] + bias[n]  (fp32 tiled 128x128x16) ----------------
__global__ __launch_bounds__(256) void gemm_bias_k(
    const float* __restrict__ A, const float* __restrict__ W,
    const float* __restrict__ bias, float* __restrict__ C,
    int M, int N, int K) {
  __shared__ __align__(16) float As[16][132];
  __shared__ __align__(16) float Ws[16][132];
  const int tid = threadIdx.x;
  const int bm = blockIdx.x * 128;
  const int bn = blockIdx.y * 128;
  const int tx = tid & 15, ty = tid >> 4;
  const int lr = tid >> 1, lc = (tid & 1) * 8;
  float acc[8][8];
#pragma unroll
  for (int i = 0; i < 8; ++i)
#pragma unroll
    for (int j = 0; j < 8; ++j) acc[i][j] = 0.f;
  const float* Ap = A + (size_t)(bm + lr) * K + lc;
  const float* Wp = W + (size_t)(bn + lr) * K + lc;
  for (int k0 = 0; k0 < K; k0 += 16) {
    float4 a0 = *(const float4*)(Ap + k0);
    float4 a1 = *(const float4*)(Ap + k0 + 4);
    float4 w0 = *(const float4*)(Wp + k0);
    float4 w1 = *(const float4*)(Wp + k0 + 4);
    __syncthreads();
    As[lc + 0][lr] = a0.x; As[lc + 1][lr] = a0.y; As[lc + 2][lr] = a0.z; As[lc + 3][lr] = a0.w;
    As[lc + 4][lr] = a1.x; As[lc + 5][lr] = a1.y; As[lc + 6][lr] = a1.z; As[lc + 7][lr] = a1.w;
    Ws[lc + 0][lr] = w0.x; Ws[lc + 1][lr] = w0.y; Ws[lc + 2][lr] = w0.z; Ws[lc + 3][lr] = w0.w;
    Ws[lc + 4][lr] = w1.x; Ws[lc + 5][lr] = w1.y; Ws[lc + 6][lr] = w1.z; Ws[lc + 7][lr] = w1.w;
    __syncthreads();
#pragma unroll
    for (int kk = 0; kk < 16; ++kk) {
      float4 av0 = *(const float4*)(&As[kk][ty * 4]);
      float4 av1 = *(const float4*)(&As[kk][64 + ty * 4]);
      float4 wv0 = *(const float4*)(&Ws[kk][tx * 4]);
      float4 wv1 = *(const float4*)(&Ws[kk][64 + tx * 4]);
      const float av[8] = {av0.x, av0.y, av0.z, av0.w, av1.x, av1.y, av1.z, av1.w};
      const float wv[8] = {wv0.x, wv0.y, wv0.z, wv0.w, wv1.x, wv1.y, wv1.z, wv1.w};
#pragma unroll
      for (int i = 0; i < 8; ++i)
#pragma unroll
        for (int j = 0; j < 8; ++j) acc[i][j] += av[i] * wv[j];
    }
  }
#pragma unroll
  for (int i = 0; i < 8; ++i) {
    const int m = bm + ((i < 4) ? (ty * 4 + i) : (64 + ty * 4 + i - 4));
#pragma unroll
    for (int j = 0; j < 8; ++j) {
      const int n = bn + ((j < 4) ? (tx * 4 + j) : (64 + tx * 4 + j - 4));
      C[(size_t)m * N + n] = acc[i][j] + bias[n];
    }
  }
}

// ---------------- attention: one block per (b,h); K row / V column-segment in registers ----------------
__global__ __launch_bounds__(256) void attn_k(
    const float* __restrict__ qg, const float* __restrict__ kg,
    const float* __restrict__ vg, float* __restrict__ xout) {
  const int bh = blockIdx.x;
  const int b = bh >> 2, h = bh & 3;
  const int tid = threadIdx.x;
  const int lane = tid & 63, w = tid >> 6;
  __shared__ __align__(16) float qs[4][64];
  __shared__ __align__(16) float pl[4][256];
  __shared__ float red[4][4];
  __shared__ float pvp[4][4][64];
  const float* kb = kg + ((size_t)b * Lc) * DMc + h * DKc;
  const float* vb = vg + ((size_t)b * Lc) * DMc + h * DKc;
  const float* qb = qg + ((size_t)b * Lc) * DMc + h * DKc;
  float kr[64], vr[64];
#pragma unroll
  for (int c4 = 0; c4 < 64; c4 += 4) {
    float4 kv = *(const float4*)(kb + (size_t)tid * DMc + c4);
    kr[c4] = kv.x; kr[c4 + 1] = kv.y; kr[c4 + 2] = kv.z; kr[c4 + 3] = kv.w;
  }
#pragma unroll
  for (int jj = 0; jj < 64; ++jj) vr[jj] = vb[(size_t)(w * 64 + jj) * DMc + lane];

  for (int q0 = 0; q0 < Lc; q0 += 4) {
    __syncthreads();  // protect qs/pl/red/pvp from previous iteration readers
    qs[w][lane] = qb[(size_t)(q0 + w) * DMc + lane];
    __syncthreads();
    // scores: thread = key index (tid)
    float s0 = 0, s1 = 0, s2 = 0, s3 = 0;
#pragma unroll
    for (int d = 0; d < 64; d += 4) {
      float4 q0v = *(const float4*)(&qs[0][d]);
      float4 q1v = *(const float4*)(&qs[1][d]);
      float4 q2v = *(const float4*)(&qs[2][d]);
      float4 q3v = *(const float4*)(&qs[3][d]);
      s0 += kr[d] * q0v.x + kr[d + 1] * q0v.y + kr[d + 2] * q0v.z + kr[d + 3] * q0v.w;
      s1 += kr[d] * q1v.x + kr[d + 1] * q1v.y + kr[d + 2] * q1v.z + kr[d + 3] * q1v.w;
      s2 += kr[d] * q2v.x + kr[d + 1] * q2v.y + kr[d + 2] * q2v.z + kr[d + 3] * q2v.w;
      s3 += kr[d] * q3v.x + kr[d + 1] * q3v.y + kr[d + 2] * q3v.z + kr[d + 3] * q3v.w;
    }
    s0 *= 0.125f; s1 *= 0.125f; s2 *= 0.125f; s3 *= 0.125f;
    float m0 = s0, m1 = s1, m2 = s2, m3 = s3;
#pragma unroll
    for (int off = 32; off > 0; off >>= 1) {
      m0 = fmaxf(m0, __shfl_xor(m0, off));
      m1 = fmaxf(m1, __shfl_xor(m1, off));
      m2 = fmaxf(m2, __shfl_xor(m2, off));
      m3 = fmaxf(m3, __shfl_xor(m3, off));
    }
    if (lane == 0) { red[w][0] = m0; red[w][1] = m1; red[w][2] = m2; red[w][3] = m3; }
    __syncthreads();
    const float M0 = fmaxf(fmaxf(red[0][0], red[1][0]), fmaxf(red[2][0], red[3][0]));
    const float M1 = fmaxf(fmaxf(red[0][1], red[1][1]), fmaxf(red[2][1], red[3][1]));
    const float M2 = fmaxf(fmaxf(red[0][2], red[1][2]), fmaxf(red[2][2], red[3][2]));
    const float M3 = fmaxf(fmaxf(red[0][3], red[1][3]), fmaxf(red[2][3], red[3][3]));
    const float e0 = expf(s0 - M0), e1 = expf(s1 - M1), e2 = expf(s2 - M2), e3 = expf(s3 - M3);
    pl[0][tid] = e0; pl[1][tid] = e1; pl[2][tid] = e2; pl[3][tid] = e3;
    float t0 = e0, t1 = e1, t2 = e2, t3 = e3;
#pragma unroll
    for (int off = 32; off > 0; off >>= 1) {
      t0 += __shfl_xor(t0, off); t1 += __shfl_xor(t1, off);
      t2 += __shfl_xor(t2, off); t3 += __shfl_xor(t3, off);
    }
    __syncthreads();  // everyone done reading red (max)
    if (lane == 0) { red[w][0] = t0; red[w][1] = t1; red[w][2] = t2; red[w][3] = t3; }
    __syncthreads();  // sums + pl visible
    // PV: thread = (key group w, dim lane)
    float a0 = 0, a1 = 0, a2 = 0, a3 = 0;
#pragma unroll
    for (int jj = 0; jj < 64; jj += 4) {
      float4 p0 = *(const float4*)(&pl[0][w * 64 + jj]);
      float4 p1 = *(const float4*)(&pl[1][w * 64 + jj]);
      float4 p2 = *(const float4*)(&pl[2][w * 64 + jj]);
      float4 p3 = *(const float4*)(&pl[3][w * 64 + jj]);
      a0 += p0.x * vr[jj] + p0.y * vr[jj + 1] + p0.z * vr[jj + 2] + p0.w * vr[jj + 3];
      a1 += p1.x * vr[jj] + p1.y * vr[jj + 1] + p1.z * vr[jj + 2] + p1.w * vr[jj + 3];
      a2 += p2.x * vr[jj] + p2.y * vr[jj + 1] + p2.z * vr[jj + 2] + p2.w * vr[jj + 3];
      a3 += p3.x * vr[jj] + p3.y * vr[jj + 1] + p3.z * vr[jj + 2] + p3.w * vr[jj + 3];
    }
    pvp[w][0][lane] = a0; pvp[w][1][lane] = a1; pvp[w][2][lane] = a2; pvp[w][3][lane] = a3;
    __syncthreads();
    const float den = red[0][w] + red[1][w] + red[2][w] + red[3][w];
    const float r = (pvp[0][w][lane] + pvp[1][w][lane] + pvp[2][w][lane] + pvp[3][w][lane]) / den;
    xout[((size_t)b * Lc + q0 + w) * DMc + h * DKc + lane] = r;
  }
}

// ---------------- BiLSTM recurrence: block (b, dir); thread = gate row, Whh row in registers ----------------
__global__ __launch_bounds__(512) void lstm_k(
    const float* __restrict__ gxf, const float* __restrict__ gxb,
    const float* __restrict__ Whhf, const float* __restrict__ Whhb,
    const float* __restrict__ bhhf, const float* __restrict__ bhhb,
    const float* __restrict__ h0, const float* __restrict__ c0,
    float* __restrict__ out) {
  const int b = blockIdx.x, dir = blockIdx.y;
  const int t = threadIdx.x;
  const float* gx = dir ? gxb : gxf;
  const float* Whh = (dir ? Whhb : Whhf) + (size_t)t * 128;
  const float bh = (dir ? bhhb : bhhf)[t];
  float w[128];
#pragma unroll
  for (int i = 0; i < 32; ++i) {
    float4 v4 = *(const float4*)(Whh + i * 4);
    w[i * 4 + 0] = v4.x; w[i * 4 + 1] = v4.y; w[i * 4 + 2] = v4.z; w[i * 4 + 3] = v4.w;
  }
  __shared__ __align__(16) float hl[128];
  __shared__ float al[512];
  float c = 0.f;
  if (t < 128) {
    hl[t] = h0[(size_t)(dir * Bc + b) * 128 + t];
    c = c0[(size_t)(dir * Bc + b) * 128 + t];
  }
  __syncthreads();
  for (int s = 0; s < Lc; ++s) {
    const int step = dir ? (Lc - 1 - s) : s;
    float acc = gx[((size_t)b * Lc + step) * 512 + t] + bh;
#pragma unroll
    for (int i = 0; i < 32; ++i) {
      float4 hv = *(const float4*)(&hl[i * 4]);
      acc += w[i * 4 + 0] * hv.x + w[i * 4 + 1] * hv.y + w[i * 4 + 2] * hv.z + w[i * 4 + 3] * hv.w;
    }
    // t<128: i(sig), 128..255: f(sig), 256..383: g(tanh), 384..511: o(sig)
    const float a = (t < 256 || t >= 384) ? (1.f / (1.f + expf(-acc))) : tanhf(acc);
    al[t] = a;
    __syncthreads();
    if (t < 128) {
      c = al[128 + t] * c + al[t] * al[256 + t];
      const float hnew = al[384 + t] * tanhf(c);
      hl[t] = hnew;
      out[((size_t)b * Lc + step) * DMc + dir * 128 + t] = hnew;
    }
    __syncthreads();
  }
}

// ---------------- logits = lstm_out @ Wout.T + bout  (N=20) ----------------
__global__ __launch_bounds__(256) void logits_k(
    const float* __restrict__ lo, const float* __restrict__ Wout,
    const float* __restrict__ bout, float* __restrict__ lg) {
  const int row = blockIdx.x;
  const int tid = threadIdx.x;
  __shared__ __align__(16) float xr[256];
  xr[tid] = lo[(size_t)row * 256 + tid];
  __syncthreads();
  if (tid < 160) {
    const int n = tid >> 3, kp = tid & 7;
    const float* wr = Wout + (size_t)n * 256 + kp * 32;
    const float* xp = xr + kp * 32;
    float s = 0.f;
#pragma unroll
    for (int k = 0; k < 32; k += 4) {
      float4 wv = *(const float4*)(wr + k);
      float4 xv = *(const float4*)(xp + k);
      s += wv.x * xv.x + wv.y * xv.y + wv.z * xv.z + wv.w * xv.w;
    }
    s += __shfl_xor(s, 1);
    s += __shfl_xor(s, 2);
    s += __shfl_xor(s, 4);
    if (kp == 0) lg[(size_t)row * NTc + n] = s + bout[n];
  }
}

// ---------------- CRF gold path score ----------------
__global__ __launch_bounds__(256) void crf_real_k(
    const float* __restrict__ lg, const int* __restrict__ tags,
    const int* __restrict__ lens, const float* __restrict__ tr,
    float* __restrict__ realv) {
  const int b = blockIdx.x, t = threadIdx.x;
  const int len = lens[b];
  float val = 0.f;
  if (t < len) {
    const int tag = tags[b * Lc + t];
    const int pv = (t == 0) ? START_c : tags[b * Lc + t - 1];
    val = lg[((size_t)b * Lc + t) * NTc + tag] + tr[pv * NTc + tag];
  }
#pragma unroll
  for (int off = 32; off > 0; off >>= 1) val += __shfl_down(val, off);
  __shared__ float r4[4];
  if ((t & 63) == 0) r4[t >> 6] = val;
  __syncthreads();
  if (t == 0) {
    const int lt = tags[b * Lc + len - 1];
    realv[b] = r4[0] + r4[1] + r4[2] + r4[3] + tr[lt * NTc + STOP_c];
  }
}

// ---------------- CRF forward (logsumexp scan), writes total - real ----------------
__global__ __launch_bounds__(64) void crf_fwd_k(
    const float* __restrict__ lg, const int* __restrict__ lens,
    const float* __restrict__ tr, const float* __restrict__ realv,
    float* __restrict__ part) {
  const int b = blockIdx.x, j = threadIdx.x;
  __shared__ float prev[NTc];
  __shared__ float tl[NTc * NTc];
  if (j < NTc) prev[j] = 0.f;
  for (int i = j; i < NTc * NTc; i += 64) tl[i] = tr[i];
  __syncthreads();
  const int len = lens[b];
  float trc[NTc];
  if (j < NTc) {
#pragma unroll
    for (int i = 0; i < NTc; ++i) trc[i] = tl[i * NTc + j];
  }
  for (int t = 0; t < len; ++t) {
    float nj = 0.f;
    if (j < NTc) {
      float v[NTc];
      float m = -1e30f;
#pragma unroll
      for (int i = 0; i < NTc; ++i) { v[i] = prev[i] + trc[i]; m = fmaxf(m, v[i]); }
      float ssum = 0.f;
#pragma unroll
      for (int i = 0; i < NTc; ++i) ssum += expf(v[i] - m);
      nj = m + logf(ssum) + lg[((size_t)b * Lc + t) * NTc + j];
    }
    __syncthreads();
    if (j < NTc) prev[j] = nj;
    __syncthreads();
  }
  if (j == 0) {
    float m = -1e30f;
#pragma unroll
    for (int i = 0; i < NTc; ++i) m = fmaxf(m, prev[i] + tl[i * NTc + STOP_c]);
    float ssum = 0.f;
#pragma unroll
    for (int i = 0; i < NTc; ++i) ssum += expf(prev[i] + tl[i * NTc + STOP_c] - m);
    part[b] = (m + logf(ssum)) - realv[b];
  }
}

__global__ __launch_bounds__(64) void final_sum_k(const float* __restrict__ part, float* __restrict__ out) {
  float v = part[threadIdx.x];
#pragma unroll
  for (int off = 32; off > 0; off >>= 1) v += __shfl_down(v, off);
  if (threadIdx.x == 0) out[0] = v;
}

extern "C" void kernel_launch(void* const* d_in, const int* in_sizes, int n_in,
                              void* d_out, int out_size, void* d_ws, size_t ws_size,
                              hipStream_t stream) {
  const int* sent = (const int*)d_in[0];
  const int* bush = (const int*)d_in[1];
  const float* pin = (const float*)d_in[2];
  const float* wz = (const float*)d_in[3];
  const float* twz = (const float*)d_in[4];
  const int* tags = (const int*)d_in[5];
  const int* lens = (const int*)d_in[6];
  const float* emb1 = (const float*)d_in[7];
  const float* emb2 = (const float*)d_in[8];
  const float* Wq = (const float*)d_in[9];  const float* bq = (const float*)d_in[10];
  const float* Wk = (const float*)d_in[11]; const float* bk = (const float*)d_in[12];
  const float* Wv = (const float*)d_in[13]; const float* bv = (const float*)d_in[14];
  const float* Wo = (const float*)d_in[15]; const float* bo = (const float*)d_in[16];
  const float* Wihf = (const float*)d_in[17]; const float* Whhf = (const float*)d_in[18];
  const float* bihf = (const float*)d_in[19]; const float* bhhf = (const float*)d_in[20];
  const float* Wihb = (const float*)d_in[21]; const float* Whhb = (const float*)d_in[22];
  const float* bihb = (const float*)d_in[23]; const float* bhhb = (const float*)d_in[24];
  const float* Wout = (const float*)d_in[25]; const float* bout = (const float*)d_in[26];
  const float* trans = (const float*)d_in[27];
  const float* h0 = (const float*)d_in[28]; const float* c0 = (const float*)d_in[29];
  float* out = (float*)d_out;
  float* w = (float*)d_ws;
  const size_t F = (size_t)ROWSc * DMc;  // 4194304 floats
  // aliasing plan (peak ~102 MB):
  float* fin = w;            // [0, F)
  float* qb = w + F;         // [F, 2F)
  float* kb = w + 2 * F;     // [2F, 3F)
  float* vb = w + 3 * F;     // [3F, 4F)
  float* attn_x = fin;       // reuse fin after QKV GEMMs
  float* xo = qb;            // reuse q after attention
  float* gxf = w + 2 * F;    // reuse k,v after attention: [2F, 4F)
  float* gxb = w + 4 * F;    // [4F, 6F)
  float* lout = fin;         // reuse attn_x after O-proj
  float* lgts = w + 6 * F;
  float* realv = lgts + (size_t)ROWSc * NTc;
  float* partv = realv + Bc;

  build_fin_k<<<ROWSc, 256, 0, stream>>>(sent, bush, pin, wz, twz, emb1, emb2, fin);
  dim3 g1(128, 2);
  gemm_bias_k<<<g1, 256, 0, stream>>>(fin, Wq, bq, qb, ROWSc, 256, 256);
  gemm_bias_k<<<g1, 256, 0, stream>>>(fin, Wk, bk, kb, ROWSc, 256, 256);
  gemm_bias_k<<<g1, 256, 0, stream>>>(fin, Wv, bv, vb, ROWSc, 256, 256);
  attn_k<<<Bc * NHc, 256, 0, stream>>>(qb, kb, vb, attn_x);
  gemm_bias_k<<<g1, 256, 0, stream>>>(attn_x, Wo, bo, xo, ROWSc, 256, 256);
  dim3 g2(128, 4);
  gemm_bias_k<<<g2, 256, 0, stream>>>(xo, Wihf, bihf, gxf, ROWSc, 512, 256);
  gemm_bias_k<<<g2, 256, 0, stream>>>(xo, Wihb, bihb, gxb, ROWSc, 512, 256);
  dim3 g3(Bc, 2);
  lstm_k<<<g3, 512, 0, stream>>>(gxf, gxb, Whhf, Whhb, bhhf, bhhb, h0, c0, lout);
  logits_k<<<ROWSc, 256, 0, stream>>>(lout, Wout, bout, lgts);
  crf_real_k<<<Bc, 256, 0, stream>>>(lgts, tags, lens, trans, realv);
  crf_fwd_k<<<Bc, 64, 0, stream>>>(lgts, lens, trans, realv, partv);
  final_sum_k<<<1, 64, 0, stream>>>(partv, out);
}

// Round 2
// 753.460 us; speedup vs baseline: 1.5680x; 1.5680x over previous
//
#include <hip/hip_runtime.h>
#include <math.h>

namespace {
constexpr int Bc = 64, Lc = 256, DMc = 256;
constexpr int NTc = 20, START_c = 18, STOP_c = 19;
constexpr int ROWSc = Bc * Lc;  // 16384
}

typedef short short8 __attribute__((ext_vector_type(8)));
typedef float f32x4 __attribute__((ext_vector_type(4)));

__device__ __forceinline__ ushort f2bf(float x) {
  unsigned u = __float_as_uint(x);
  unsigned r = (u + 0x7FFFu + ((u >> 16) & 1u)) >> 16;
  return (ushort)r;
}
__device__ __forceinline__ float bf2f(ushort h) {
  return __uint_as_float((unsigned)h << 16);
}
__device__ __forceinline__ float fast_sig(float x) {
  return __fdividef(1.f, 1.f + __expf(-x));
}
__device__ __forceinline__ float fast_tanh(float x) {
  return 1.f - __fdividef(2.f, 1.f + __expf(2.f * x));
}

// ---------------- fin (bf16) = concat(emb1[sent], emb2[bush], pinyin, trans_weizhi, weizhi) ----------------
__global__ __launch_bounds__(256) void build_fin_k(
    const int* __restrict__ sent, const int* __restrict__ bush,
    const float* __restrict__ pin, const float* __restrict__ wz,
    const float* __restrict__ twz, const float* __restrict__ emb1,
    const float* __restrict__ emb2, ushort* __restrict__ finb) {
  const int row = blockIdx.x;
  const int c = threadIdx.x;
  float v;
  if (c < 100)      v = emb1[(size_t)sent[row] * 100 + c];
  else if (c < 200) v = emb2[(size_t)bush[row] * 100 + (c - 100)];
  else if (c < 220) v = pin[(size_t)row * 20 + (c - 200)];
  else if (c < 238) v = twz[(size_t)row * 18 + (c - 220)];
  else              v = wz[(size_t)row * 18 + (c - 238)];
  finb[(size_t)row * 256 + c] = f2bf(v);
}

// ---------------- pack weights/biases to bf16: wqkv[768][256], wih[1024][256], wo[256][256] ----------------
__global__ __launch_bounds__(256) void pack_weights_k(
    const float* __restrict__ Wq, const float* __restrict__ Wk,
    const float* __restrict__ Wv, const float* __restrict__ Wo,
    const float* __restrict__ Wihf, const float* __restrict__ Wihb,
    const float* __restrict__ bq, const float* __restrict__ bk,
    const float* __restrict__ bv, const float* __restrict__ bihf,
    const float* __restrict__ bihb,
    ushort* __restrict__ wqkv, ushort* __restrict__ wih, ushort* __restrict__ wo,
    float* __restrict__ bqkv, float* __restrict__ bih) {
  const int gid = blockIdx.x * 256 + threadIdx.x;  // 65536 threads
  const int row = gid >> 5;
  const int cl = (gid & 31) * 8;
  const float* src;
  ushort* dst;
  if (row < 768) {
    src = (row < 256 ? Wq : (row < 512 ? Wk : Wv)) + (size_t)(row & 255) * 256;
    dst = wqkv + (size_t)row * 256;
  } else if (row < 1792) {
    const int rr = row - 768;
    src = (rr < 512 ? Wihf + (size_t)rr * 256 : Wihb + (size_t)(rr - 512) * 256);
    dst = wih + (size_t)rr * 256;
  } else {
    const int rr = row - 1792;
    src = Wo + (size_t)rr * 256;
    dst = wo + (size_t)rr * 256;
  }
  float4 v0 = *(const float4*)(src + cl);
  float4 v1 = *(const float4*)(src + cl + 4);
  short8 o;
  o[0] = (short)f2bf(v0.x); o[1] = (short)f2bf(v0.y); o[2] = (short)f2bf(v0.z); o[3] = (short)f2bf(v0.w);
  o[4] = (short)f2bf(v1.x); o[5] = (short)f2bf(v1.y); o[6] = (short)f2bf(v1.z); o[7] = (short)f2bf(v1.w);
  *(short8*)(dst + cl) = o;
  if (gid < 768) {
    bqkv[gid] = (gid < 256 ? bq[gid] : (gid < 512 ? bk[gid - 256] : bv[gid - 512]));
  } else if (gid < 1792) {
    bih[gid - 768] = (gid < 1280 ? bihf[gid - 768] : bihb[gid - 1280]);
  }
}

// ---------------- bf16 MFMA GEMM: C[m,n] = sum_k A[m,k]*W[n,k] + bias[n]; K=256, 128x128 tile ----------------
template <int N, bool BF16_OUT>
__global__ __launch_bounds__(256, 2) void mfma_gemm_k(
    const ushort* __restrict__ A, const ushort* __restrict__ W,
    const float* __restrict__ bias, void* __restrict__ Cv) {
  const int tid = threadIdx.x, lane = tid & 63, wid = tid >> 6;
  const int bm = blockIdx.x * 128, bn = blockIdx.y * 128;
  const int wm = (wid >> 1) * 64, wn = (wid & 1) * 64;
  const int r = lane & 15, kg = lane >> 4;
  const ushort* Ap = A + (size_t)(bm + wm + r) * 256 + kg * 8;
  const ushort* Wp = W + (size_t)(bn + wn + r) * 256 + kg * 8;
  f32x4 acc[4][4];
#pragma unroll
  for (int i = 0; i < 4; ++i)
#pragma unroll
    for (int j = 0; j < 4; ++j) acc[i][j] = (f32x4){0.f, 0.f, 0.f, 0.f};
#pragma unroll
  for (int k0 = 0; k0 < 256; k0 += 32) {
    short8 a[4], b[4];
#pragma unroll
    for (int fi = 0; fi < 4; ++fi) a[fi] = *(const short8*)(Ap + fi * 16 * 256 + k0);
#pragma unroll
    for (int fj = 0; fj < 4; ++fj) b[fj] = *(const short8*)(Wp + fj * 16 * 256 + k0);
#pragma unroll
    for (int fi = 0; fi < 4; ++fi)
#pragma unroll
      for (int fj = 0; fj < 4; ++fj)
        acc[fi][fj] = __builtin_amdgcn_mfma_f32_16x16x32_bf16(a[fi], b[fj], acc[fi][fj], 0, 0, 0);
  }
#pragma unroll
  for (int fi = 0; fi < 4; ++fi)
#pragma unroll
    for (int fj = 0; fj < 4; ++fj) {
      const int n = bn + wn + fj * 16 + r;
      const float bn_ = bias[n];
#pragma unroll
      for (int rr = 0; rr < 4; ++rr) {
        const int m = bm + wm + fi * 16 + kg * 4 + rr;
        const float v = acc[fi][fj][rr] + bn_;
        if (BF16_OUT) ((ushort*)Cv)[(size_t)m * N + n] = f2bf(v);
        else          ((float*)Cv)[(size_t)m * N + n] = v;
      }
    }
}

// ---------------- attention: one block per (b,h); qkv packed [ROWS][768] fp32; out bf16 [ROWS][256] ----------
__global__ __launch_bounds__(256) void attn_k(
    const float* __restrict__ qkv, ushort* __restrict__ xout) {
  const int bh = blockIdx.x;
  const int b = bh >> 2, h = bh & 3;
  const int tid = threadIdx.x;
  const int lane = tid & 63, w = tid >> 6;
  __shared__ __align__(16) float qs[4][64];
  __shared__ __align__(16) float pl[4][256];
  __shared__ float red[4][4];
  __shared__ float pvp[4][4][64];
  const float* qb = qkv + (size_t)(b * Lc) * 768 + h * 64;
  const float* kb = qb + 256;
  const float* vb = qb + 512;
  float kr[64], vr[64];
#pragma unroll
  for (int c4 = 0; c4 < 64; c4 += 4) {
    float4 kv = *(const float4*)(kb + (size_t)tid * 768 + c4);
    kr[c4] = kv.x; kr[c4 + 1] = kv.y; kr[c4 + 2] = kv.z; kr[c4 + 3] = kv.w;
  }
#pragma unroll
  for (int jj = 0; jj < 64; ++jj) vr[jj] = vb[(size_t)(w * 64 + jj) * 768 + lane];

  for (int q0 = 0; q0 < Lc; q0 += 4) {
    __syncthreads();
    qs[w][lane] = qb[(size_t)(q0 + w) * 768 + lane];
    __syncthreads();
    float s0 = 0, s1 = 0, s2 = 0, s3 = 0;
#pragma unroll
    for (int d = 0; d < 64; d += 4) {
      float4 q0v = *(const float4*)(&qs[0][d]);
      float4 q1v = *(const float4*)(&qs[1][d]);
      float4 q2v = *(const float4*)(&qs[2][d]);
      float4 q3v = *(const float4*)(&qs[3][d]);
      s0 += kr[d] * q0v.x + kr[d + 1] * q0v.y + kr[d + 2] * q0v.z + kr[d + 3] * q0v.w;
      s1 += kr[d] * q1v.x + kr[d + 1] * q1v.y + kr[d + 2] * q1v.z + kr[d + 3] * q1v.w;
      s2 += kr[d] * q2v.x + kr[d + 1] * q2v.y + kr[d + 2] * q2v.z + kr[d + 3] * q2v.w;
      s3 += kr[d] * q3v.x + kr[d + 1] * q3v.y + kr[d + 2] * q3v.z + kr[d + 3] * q3v.w;
    }
    s0 *= 0.125f; s1 *= 0.125f; s2 *= 0.125f; s3 *= 0.125f;
    float m0 = s0, m1 = s1, m2 = s2, m3 = s3;
#pragma unroll
    for (int off = 32; off > 0; off >>= 1) {
      m0 = fmaxf(m0, __shfl_xor(m0, off));
      m1 = fmaxf(m1, __shfl_xor(m1, off));
      m2 = fmaxf(m2, __shfl_xor(m2, off));
      m3 = fmaxf(m3, __shfl_xor(m3, off));
    }
    if (lane == 0) { red[w][0] = m0; red[w][1] = m1; red[w][2] = m2; red[w][3] = m3; }
    __syncthreads();
    const float M0 = fmaxf(fmaxf(red[0][0], red[1][0]), fmaxf(red[2][0], red[3][0]));
    const float M1 = fmaxf(fmaxf(red[0][1], red[1][1]), fmaxf(red[2][1], red[3][1]));
    const float M2 = fmaxf(fmaxf(red[0][2], red[1][2]), fmaxf(red[2][2], red[3][2]));
    const float M3 = fmaxf(fmaxf(red[0][3], red[1][3]), fmaxf(red[2][3], red[3][3]));
    const float e0 = __expf(s0 - M0), e1 = __expf(s1 - M1), e2 = __expf(s2 - M2), e3 = __expf(s3 - M3);
    pl[0][tid] = e0; pl[1][tid] = e1; pl[2][tid] = e2; pl[3][tid] = e3;
    float t0 = e0, t1 = e1, t2 = e2, t3 = e3;
#pragma unroll
    for (int off = 32; off > 0; off >>= 1) {
      t0 += __shfl_xor(t0, off); t1 += __shfl_xor(t1, off);
      t2 += __shfl_xor(t2, off); t3 += __shfl_xor(t3, off);
    }
    __syncthreads();
    if (lane == 0) { red[w][0] = t0; red[w][1] = t1; red[w][2] = t2; red[w][3] = t3; }
    __syncthreads();
    float a0 = 0, a1 = 0, a2 = 0, a3 = 0;
#pragma unroll
    for (int jj = 0; jj < 64; jj += 4) {
      float4 p0 = *(const float4*)(&pl[0][w * 64 + jj]);
      float4 p1 = *(const float4*)(&pl[1][w * 64 + jj]);
      float4 p2 = *(const float4*)(&pl[2][w * 64 + jj]);
      float4 p3 = *(const float4*)(&pl[3][w * 64 + jj]);
      a0 += p0.x * vr[jj] + p0.y * vr[jj + 1] + p0.z * vr[jj + 2] + p0.w * vr[jj + 3];
      a1 += p1.x * vr[jj] + p1.y * vr[jj + 1] + p1.z * vr[jj + 2] + p1.w * vr[jj + 3];
      a2 += p2.x * vr[jj] + p2.y * vr[jj + 1] + p2.z * vr[jj + 2] + p2.w * vr[jj + 3];
      a3 += p3.x * vr[jj] + p3.y * vr[jj + 1] + p3.z * vr[jj + 2] + p3.w * vr[jj + 3];
    }
    pvp[w][0][lane] = a0; pvp[w][1][lane] = a1; pvp[w][2][lane] = a2; pvp[w][3][lane] = a3;
    __syncthreads();
    const float den = red[0][w] + red[1][w] + red[2][w] + red[3][w];
    const float rres = (pvp[0][w][lane] + pvp[1][w][lane] + pvp[2][w][lane] + pvp[3][w][lane]) / den;
    xout[((size_t)b * Lc + q0 + w) * 256 + h * 64 + lane] = f2bf(rres);
  }
}

// ---------------- BiLSTM recurrence: block (b,dir); thread=(unit u, gate q); Whh row in VGPRs ----------------
// gx: bf16 [ROWS][1024], forward gates cols 0..511, backward 512..1023
__global__ __launch_bounds__(512, 2) void lstm_k(
    const ushort* __restrict__ gx,
    const float* __restrict__ Whhf, const float* __restrict__ Whhb,
    const float* __restrict__ bhhf, const float* __restrict__ bhhb,
    const float* __restrict__ h0, const float* __restrict__ c0,
    float* __restrict__ out) {
  const int b = blockIdx.x, dir = blockIdx.y;
  const int tid = threadIdx.x;
  const int lane = tid & 63, wv = tid >> 6;
  const int u = wv * 16 + (lane >> 2);  // hidden unit 0..127
  const int q = lane & 3;               // gate: 0=i 1=f 2=g 3=o
  const int grow = q * 128 + u;
  const float* Whh = (dir ? Whhb : Whhf) + (size_t)grow * 128;
  const float bh = (dir ? bhhb : bhhf)[grow];
  float w[128];
#pragma unroll
  for (int i = 0; i < 32; ++i) {
    float4 t4 = *(const float4*)(Whh + i * 4);
    w[4 * i] = t4.x; w[4 * i + 1] = t4.y; w[4 * i + 2] = t4.z; w[4 * i + 3] = t4.w;
  }
  __shared__ __align__(16) float hb[2][128];
  if (tid < 128) hb[0][tid] = h0[(size_t)(dir * Bc + b) * 128 + tid];
  float c = c0[(size_t)(dir * Bc + b) * 128 + u];
  const ushort* gp = gx + dir * 512 + grow;
  const int step0 = dir ? (Lc - 1) : 0;
  float gnext = bf2f(gp[(size_t)(b * Lc + step0) * 1024]);
  __syncthreads();
  int rdbuf = 0;
  for (int s = 0; s < Lc; ++s) {
    float acc0 = gnext + bh, acc1 = 0.f, acc2 = 0.f, acc3 = 0.f;
    if (s + 1 < Lc) {
      const int stepn = dir ? (Lc - 2 - s) : (s + 1);
      gnext = bf2f(gp[(size_t)(b * Lc + stepn) * 1024]);
    }
    const float* hq = hb[rdbuf];
#pragma unroll
    for (int i = 0; i < 8; ++i) {
      float4 h0v = *(const float4*)(hq + i * 16);
      float4 h1v = *(const float4*)(hq + i * 16 + 4);
      float4 h2v = *(const float4*)(hq + i * 16 + 8);
      float4 h3v = *(const float4*)(hq + i * 16 + 12);
      acc0 += w[i*16+0]*h0v.x + w[i*16+1]*h0v.y + w[i*16+2]*h0v.z + w[i*16+3]*h0v.w;
      acc1 += w[i*16+4]*h1v.x + w[i*16+5]*h1v.y + w[i*16+6]*h1v.z + w[i*16+7]*h1v.w;
      acc2 += w[i*16+8]*h2v.x + w[i*16+9]*h2v.y + w[i*16+10]*h2v.z + w[i*16+11]*h2v.w;
      acc3 += w[i*16+12]*h3v.x + w[i*16+13]*h3v.y + w[i*16+14]*h3v.z + w[i*16+15]*h3v.w;
    }
    const float g = (acc0 + acc1) + (acc2 + acc3);
    const float a = (q == 2) ? fast_tanh(g) : fast_sig(g);
    // quad exchange: gather all 4 activated gates
    const float b1 = __shfl_xor(a, 1);
    const float e0 = (q & 1) ? b1 : a;   // gate (q&~1)+0
    const float e1 = (q & 1) ? a : b1;   // gate (q&~1)+1
    const float f0 = __shfl_xor(e0, 2);
    const float f1 = __shfl_xor(e1, 2);
    const float gi = (q & 2) ? f0 : e0;
    const float gf = (q & 2) ? f1 : e1;
    const float gg = (q & 2) ? e0 : f0;
    const float go = (q & 2) ? e1 : f1;
    c = gf * c + gi * gg;
    const float hn = go * fast_tanh(c);
    const int step = dir ? (Lc - 1 - s) : s;
    if (q == 0) {
      hb[rdbuf ^ 1][u] = hn;
      out[((size_t)(b * Lc + step)) * DMc + dir * 128 + u] = hn;
    }
    rdbuf ^= 1;
    __syncthreads();
  }
}

// ---------------- logits = lstm_out @ Wout.T + bout  (N=20) ----------------
__global__ __launch_bounds__(256) void logits_k(
    const float* __restrict__ lo, const float* __restrict__ Wout,
    const float* __restrict__ bout, float* __restrict__ lg) {
  const int row = blockIdx.x;
  const int tid = threadIdx.x;
  __shared__ __align__(16) float xr[256];
  xr[tid] = lo[(size_t)row * 256 + tid];
  __syncthreads();
  if (tid < 160) {
    const int n = tid >> 3, kp = tid & 7;
    const float* wr = Wout + (size_t)n * 256 + kp * 32;
    const float* xp = xr + kp * 32;
    float s = 0.f;
#pragma unroll
    for (int k = 0; k < 32; k += 4) {
      float4 wv = *(const float4*)(wr + k);
      float4 xv = *(const float4*)(xp + k);
      s += wv.x * xv.x + wv.y * xv.y + wv.z * xv.z + wv.w * xv.w;
    }
    s += __shfl_xor(s, 1);
    s += __shfl_xor(s, 2);
    s += __shfl_xor(s, 4);
    if (kp == 0) lg[(size_t)row * NTc + n] = s + bout[n];
  }
}

// ---------------- CRF gold path score ----------------
__global__ __launch_bounds__(256) void crf_real_k(
    const float* __restrict__ lg, const int* __restrict__ tags,
    const int* __restrict__ lens, const float* __restrict__ tr,
    float* __restrict__ realv) {
  const int b = blockIdx.x, t = threadIdx.x;
  const int len = lens[b];
  float val = 0.f;
  if (t < len) {
    const int tag = tags[b * Lc + t];
    const int pv = (t == 0) ? START_c : tags[b * Lc + t - 1];
    val = lg[((size_t)b * Lc + t) * NTc + tag] + tr[pv * NTc + tag];
  }
#pragma unroll
  for (int off = 32; off > 0; off >>= 1) val += __shfl_down(val, off);
  __shared__ float r4[4];
  if ((t & 63) == 0) r4[t >> 6] = val;
  __syncthreads();
  if (t == 0) {
    const int lt = tags[b * Lc + len - 1];
    realv[b] = r4[0] + r4[1] + r4[2] + r4[3] + tr[lt * NTc + STOP_c];
  }
}

// ---------------- CRF forward (logsumexp scan), writes total - real ----------------
__global__ __launch_bounds__(64) void crf_fwd_k(
    const float* __restrict__ lg, const int* __restrict__ lens,
    const float* __restrict__ tr, const float* __restrict__ realv,
    float* __restrict__ part) {
  const int b = blockIdx.x, j = threadIdx.x;
  __shared__ float prev[NTc];
  __shared__ float tl[NTc * NTc];
  if (j < NTc) prev[j] = 0.f;
  for (int i = j; i < NTc * NTc; i += 64) tl[i] = tr[i];
  __syncthreads();
  const int len = lens[b];
  float trc[NTc];
  if (j < NTc) {
#pragma unroll
    for (int i = 0; i < NTc; ++i) trc[i] = tl[i * NTc + j];
  }
  float lgn = (j < NTc) ? lg[((size_t)b * Lc) * NTc + j] : 0.f;
  for (int t = 0; t < len; ++t) {
    const float lgc = lgn;
    float nj = 0.f;
    if (j < NTc) {
      if (t + 1 < len) lgn = lg[((size_t)b * Lc + t + 1) * NTc + j];
      float v[NTc];
      float m = -1e30f;
#pragma unroll
      for (int i = 0; i < NTc; ++i) { v[i] = prev[i] + trc[i]; m = fmaxf(m, v[i]); }
      float ssum = 0.f;
#pragma unroll
      for (int i = 0; i < NTc; ++i) ssum += __expf(v[i] - m);
      nj = m + __logf(ssum) + lgc;
    }
    __syncthreads();
    if (j < NTc) prev[j] = nj;
    __syncthreads();
  }
  if (j == 0) {
    float m = -1e30f;
#pragma unroll
    for (int i = 0; i < NTc; ++i) m = fmaxf(m, prev[i] + tl[i * NTc + STOP_c]);
    float ssum = 0.f;
#pragma unroll
    for (int i = 0; i < NTc; ++i) ssum += __expf(prev[i] + tl[i * NTc + STOP_c] - m);
    part[b] = (m + __logf(ssum)) - realv[b];
  }
}

__global__ __launch_bounds__(64) void final_sum_k(const float* __restrict__ part, float* __restrict__ out) {
  float v = part[threadIdx.x];
#pragma unroll
  for (int off = 32; off > 0; off >>= 1) v += __shfl_down(v, off);
  if (threadIdx.x == 0) out[0] = v;
}

extern "C" void kernel_launch(void* const* d_in, const int* in_sizes, int n_in,
                              void* d_out, int out_size, void* d_ws, size_t ws_size,
                              hipStream_t stream) {
  const int* sent = (const int*)d_in[0];
  const int* bush = (const int*)d_in[1];
  const float* pin = (const float*)d_in[2];
  const float* wz = (const float*)d_in[3];
  const float* twz = (const float*)d_in[4];
  const int* tags = (const int*)d_in[5];
  const int* lens = (const int*)d_in[6];
  const float* emb1 = (const float*)d_in[7];
  const float* emb2 = (const float*)d_in[8];
  const float* Wq = (const float*)d_in[9];  const float* bq = (const float*)d_in[10];
  const float* Wk = (const float*)d_in[11]; const float* bk = (const float*)d_in[12];
  const float* Wv = (const float*)d_in[13]; const float* bv = (const float*)d_in[14];
  const float* Wo = (const float*)d_in[15]; const float* bo = (const float*)d_in[16];
  const float* Wihf = (const float*)d_in[17]; const float* Whhf = (const float*)d_in[18];
  const float* bihf = (const float*)d_in[19]; const float* bhhf = (const float*)d_in[20];
  const float* Wihb = (const float*)d_in[21]; const float* Whhb = (const float*)d_in[22];
  const float* bihb = (const float*)d_in[23]; const float* bhhb = (const float*)d_in[24];
  const float* Wout = (const float*)d_in[25]; const float* bout = (const float*)d_in[26];
  const float* trans = (const float*)d_in[27];
  const float* h0 = (const float*)d_in[28]; const float* c0 = (const float*)d_in[29];
  float* out = (float*)d_out;
  float* w = (float*)d_ws;
  const size_t F = (size_t)ROWSc * DMc;  // 4194304 floats
  // layout (floats): total ~17.4M floats = 70 MB
  ushort* finb = (ushort*)w;                 // [0, F/2): 16384x256 bf16
  ushort* axb  = (ushort*)w;                 // reuse after QKV GEMM
  float*  qkv  = w + F / 2;                  // [F/2, F/2+3F): 16384x768 f32
  ushort* xob  = (ushort*)(w + F / 2);       // reuse qkv region after attn
  ushort* gxb  = (ushort*)(w + F);           // [F, 3F): 16384x1024 bf16
  float*  lout = w + 3 * F;                  // [3F, 4F): 16384x256 f32
  float*  lgts = w + 4 * F;                  // 16384x20
  size_t off = 4 * F + (size_t)ROWSc * NTc;
  ushort* wqkvb = (ushort*)(w + off); off += 768 * 256 / 2;
  ushort* wihbf = (ushort*)(w + off); off += 1024 * 256 / 2;
  ushort* wob   = (ushort*)(w + off); off += 256 * 256 / 2;
  float* bqkv = w + off; off += 768;
  float* bihp = w + off; off += 1024;
  float* realv = w + off; off += 64;
  float* partv = w + off;

  build_fin_k<<<ROWSc, 256, 0, stream>>>(sent, bush, pin, wz, twz, emb1, emb2, finb);
  pack_weights_k<<<256, 256, 0, stream>>>(Wq, Wk, Wv, Wo, Wihf, Wihb, bq, bk, bv, bihf, bihb,
                                          wqkvb, wihbf, wob, bqkv, bihp);
  mfma_gemm_k<768, false><<<dim3(128, 6), 256, 0, stream>>>(finb, wqkvb, bqkv, qkv);
  attn_k<<<Bc * 4, 256, 0, stream>>>(qkv, axb);
  mfma_gemm_k<256, true><<<dim3(128, 2), 256, 0, stream>>>(axb, wob, bo, xob);
  mfma_gemm_k<1024, true><<<dim3(128, 8), 256, 0, stream>>>(xob, wihbf, bihp, gxb);
  dim3 g3(Bc, 2);
  lstm_k<<<g3, 512, 0, stream>>>(gxb, Whhf, Whhb, bhhf, bhhb, h0, c0, lout);
  logits_k<<<ROWSc, 256, 0, stream>>>(lout, Wout, bout, lgts);
  crf_real_k<<<Bc, 256, 0, stream>>>(lgts, tags, lens, trans, realv);
  crf_fwd_k<<<Bc, 64, 0, stream>>>(lgts, lens, trans, realv, partv);
  final_sum_k<<<1, 64, 0, stream>>>(partv, out);
}